// Round 2
// 1381.736 us; speedup vs baseline: 1.1460x; 1.1460x over previous
//
#include <hip/hip_runtime.h>
#include <stdint.h>

// Problem dims (fixed): T=256, B=128, I=512, H=1024, O=1
typedef __attribute__((ext_vector_type(8))) short short8;
typedef __attribute__((ext_vector_type(4))) float f32x4;
typedef __attribute__((ext_vector_type(4))) unsigned int u32x4;

__device__ __forceinline__ unsigned short f2bf(float f) {
  unsigned u = __float_as_uint(f);
  u += 0x7FFFu + ((u >> 16) & 1u);   // RNE
  return (unsigned short)(u >> 16);
}
__device__ __forceinline__ float bf2f(unsigned short s) {
  return __uint_as_float(((unsigned)s) << 16);
}
__device__ __forceinline__ float ftanh(float x) {
  float e = __expf(2.0f * x);
  return 1.0f - 2.0f / (e + 1.0f);
}

// ---------------- fp32 -> bf16 convert (vectorized, 8 elem/thread) ----------
__global__ __launch_bounds__(256) void cvt_kernel(const float* __restrict__ in,
                                                  unsigned short* __restrict__ out,
                                                  int n8) {
  int i = blockIdx.x * 256 + threadIdx.x;
  if (i >= n8) return;
  const float4* p = (const float4*)in + (size_t)i * 2;
  float4 a = p[0], b = p[1];
  uint4 o;
  o.x = (unsigned)f2bf(a.x) | ((unsigned)f2bf(a.y) << 16);
  o.y = (unsigned)f2bf(a.z) | ((unsigned)f2bf(a.w) << 16);
  o.z = (unsigned)f2bf(b.x) | ((unsigned)f2bf(b.y) << 16);
  o.w = (unsigned)f2bf(b.z) | ((unsigned)f2bf(b.w) << 16);
  ((uint4*)out)[i] = o;
}

// ---------------- re-poison hs strips 1..131 (aliased by dead xb/wb) --------
// The sentinel protocol needs every readable hs strip to be 0xAA-poison
// before the first publish. Strips 1..127 alias xb (bf16 x), 128..131 alias
// wb (bf16 W_ih) -- both dead after gemm_xp. Separate dispatch => complete
// before any scan publish; kernel-end release flushes dirty L2 to MALL.
__global__ __launch_bounds__(256) void scrub_kernel(unsigned* __restrict__ dst,
                                                    int n4) {
  int i = blockIdx.x * 256 + threadIdx.x;
  if (i >= n4) return;
  ((u32x4*)dst)[i] = (u32x4){0xAAAAAAAAu, 0xAAAAAAAAu, 0xAAAAAAAAu, 0xAAAAAAAAu};
}

// ---------------- xp GEMM: xp[m][n] = sum_k x[m][k]*W_ih[n][k] + b_ih[n]+b_hh[n]
__global__ __launch_bounds__(256) void gemm_xp(const unsigned short* __restrict__ A,
                                               const unsigned short* __restrict__ Bw,
                                               const float* __restrict__ b_ih,
                                               const float* __restrict__ b_hh,
                                               unsigned short* __restrict__ xp) {
  __shared__ unsigned short Al[8192];
  __shared__ unsigned short Bl[8192];
  int tid = threadIdx.x, lane = tid & 63, w = tid >> 6;
  int wm = w & 1, wn = w >> 1;
  int bx = blockIdx.x;
  int m0 = (bx >> 3) * 128, n0 = (bx & 7) * 128;

  f32x4 acc[4][4];
#pragma unroll
  for (int i = 0; i < 4; ++i)
#pragma unroll
    for (int jq = 0; jq < 4; ++jq) acc[i][jq] = (f32x4){0.f, 0.f, 0.f, 0.f};

  for (int kb = 0; kb < 512; kb += 64) {
#pragma unroll
    for (int i = 0; i < 4; ++i) {
      int S = (w * 4 + i) * 64 + lane;
      int row = S >> 3, pg = S & 7;
      int gk = ((pg ^ (row & 7)) << 3);
      const unsigned short* ga = A + (size_t)(m0 + row) * 512 + kb + gk;
      const unsigned short* gb = Bw + (size_t)(n0 + row) * 512 + kb + gk;
      __builtin_amdgcn_global_load_lds(
          (const __attribute__((address_space(1))) unsigned int*)ga,
          (__attribute__((address_space(3))) unsigned int*)&Al[(size_t)((w * 4 + i) * 64) * 8],
          16, 0, 0);
      __builtin_amdgcn_global_load_lds(
          (const __attribute__((address_space(1))) unsigned int*)gb,
          (__attribute__((address_space(3))) unsigned int*)&Bl[(size_t)((w * 4 + i) * 64) * 8],
          16, 0, 0);
    }
    asm volatile("s_waitcnt vmcnt(0)" ::: "memory");
    __syncthreads();

#pragma unroll
    for (int c = 0; c < 2; ++c) {
      short8 av[4], bv[4];
      int gg = c * 4 + (lane >> 4);
#pragma unroll
      for (int mt = 0; mt < 4; ++mt) {
        int rowa = wm * 64 + mt * 16 + (lane & 15);
        av[mt] = *(const short8*)&Al[(rowa * 8 + (gg ^ (rowa & 7))) * 8];
        int rowb = wn * 64 + mt * 16 + (lane & 15);
        bv[mt] = *(const short8*)&Bl[(rowb * 8 + (gg ^ (rowb & 7))) * 8];
      }
#pragma unroll
      for (int mt = 0; mt < 4; ++mt)
#pragma unroll
        for (int nt = 0; nt < 4; ++nt)
          acc[mt][nt] = __builtin_amdgcn_mfma_f32_16x16x32_bf16(av[mt], bv[nt], acc[mt][nt], 0, 0, 0);
    }
    __syncthreads();
  }

  int cl = lane & 15, qd = lane >> 4;
#pragma unroll
  for (int nt = 0; nt < 4; ++nt) {
    int col = n0 + wn * 64 + nt * 16 + cl;
    float bias = b_ih[col] + b_hh[col];
#pragma unroll
    for (int mt = 0; mt < 4; ++mt) {
#pragma unroll
      for (int r = 0; r < 4; ++r) {
        int m = m0 + wm * 64 + mt * 16 + qd * 4 + r;
        xp[(size_t)m * 1024 + col] = f2bf(acc[mt][nt][r] + bias);
      }
    }
  }
}

// ---------------- the scan + fused head ------------------------------------
// 64 WGs x 512 threads (8 waves): group g = blk>>3 (16 batches), producer
// p = blk&7 owns cols [p*128, p*128+128); wave w owns the 16x16 tile at
// cols p*128+w*16. W_hh B-frags: 128 VGPRs/wave. Rendezvous protocol
// (r2-proven base, minus the tag subsystem): publishes are sc0 sc1
// write-through-to-MALL dwordx4 at fresh per-step addresses; consumers
// validate the DATA itself against the 0xAAAAAAAA workspace poison --
// each 16B chunk is written by exactly one dwordx4, so any dword still
// equal to poison means "not yet published" (>=4B store atomicity makes
// tearing detectable). First attempt is a plain cached load; retries use
// sc0 sc1 (L1/L2 bypass) so a stale poisoned cache line can never wedge.
// This removes producer vmcnt-ack, tag store, tag trip, and poll-detect
// trip from the serial chain. False-ready needs a published bf16 pair to
// equal exactly (0xAAAA,0xAAAA) ~= (-1.9e-13,-1.9e-13): P ~ 1e-23/run.
// Head (O=1) fused via shfl-reduce + atomicAdd off the critical path.
// launch_bounds (512,1): only 64 blocks on 256 CUs -> 1 block/CU anyway;
// frees the register allocator to 256 VGPRs (no spill for retry temps).
__global__ __launch_bounds__(512, 1) void scan_kernel(
    const float* __restrict__ Whh, const unsigned short* __restrict__ xp,
    const float* __restrict__ Wfc, const float* __restrict__ bfc,
    unsigned short* __restrict__ hs, float* __restrict__ out) {
  __shared__ __align__(16) unsigned short Abuf[2048 * 8];     // 32 KB, piece m @ Abuf[m*8]
  __shared__ __align__(16) unsigned short ptile[8][16 * 32];  // 8 KB pack tiles
  const int tid = threadIdx.x;
  const int lane = tid & 63, w = tid >> 6;
  const int g = blockIdx.x >> 3, p = blockIdx.x & 7;
  const int r = lane & 15, q = lane >> 4;
  const int b0 = g * 16;
  const int gcol = p * 128 + w * 16 + r;   // this lane's output column
  const float bfcv = bfc[0];
  const float wfcv = Wfc[gcol];

  // ---- W_hh -> register B-frags: lane (r,q) holds W[gcol][c*32+q*8 ..+7]
  short8 Bfrag[32];
  {
    const float* wsrc = Whh + (size_t)gcol * 1024 + q * 8;
#pragma unroll
    for (int c = 0; c < 32; ++c) {
      float4 v0 = *(const float4*)(wsrc + c * 32);
      float4 v1 = *(const float4*)(wsrc + c * 32 + 4);
      short8 sv;
      sv[0] = (short)f2bf(v0.x); sv[1] = (short)f2bf(v0.y);
      sv[2] = (short)f2bf(v0.z); sv[3] = (short)f2bf(v0.w);
      sv[4] = (short)f2bf(v1.x); sv[5] = (short)f2bf(v1.y);
      sv[6] = (short)f2bf(v1.z); sv[7] = (short)f2bf(v1.w);
      Bfrag[c] = sv;
    }
  }

  // ---- step 0: full h0 = tanh(xp[0]) for this group, locally, into Abuf.
  // Piece m (c=m>>6, l=m&63): batch l&15, cols c*32 + (l>>4)*8 ..+7.
  {
#pragma unroll
    for (int i = 0; i < 4; ++i) {
      int m = tid + i * 512;
      int l = m & 63, c = m >> 6;
      int bb = l & 15, q2 = l >> 4;
      const unsigned short* src = xp + (size_t)(b0 + bb) * 1024 + c * 32 + q2 * 8;
      u32x4 xv = *(const u32x4*)src;
      const unsigned short* xs = (const unsigned short*)&xv;
      short8 sv;
      float pp = 0.f;
#pragma unroll
      for (int jj = 0; jj < 8; ++jj) {
        float h = ftanh(bf2f(xs[jj]));
        sv[jj] = (short)f2bf(h);
        pp += h * Wfc[c * 32 + q2 * 8 + jj];
      }
      *(short8*)&Abuf[(size_t)m * 8] = sv;
      if (p == 0) {               // head t=0: one WG per group contributes
        if (m < 16) pp += bfcv;   // c==0,q2==0: once per batch
        atomicAdd(out + b0 + bb, pp);
      }
    }
  }
  __syncthreads();  // Abuf(h0) ready for s=1

  for (int s = 1; s < 256; ++s) {
    if (s >= 2) {
      __syncthreads();  // B1: prev step's Abuf reads done; safe to refill

      // ---- validated strip load of h[s-1] -> Abuf. 4 chunks/thread.
      const unsigned short* hbase = hs + (size_t)(s - 1) * 131072;
      u32x4 v0, v1, v2, v3;
      const u32x4 *s0, *s1, *s2, *s3;
      {
        int m, l, c, bb, q2;
        m = tid;           l = m & 63; c = m >> 6; bb = l & 15; q2 = l >> 4;
        s0 = (const u32x4*)(hbase + (size_t)(b0 + bb) * 1024 + c * 32 + q2 * 8);
        m = tid + 512;     l = m & 63; c = m >> 6; bb = l & 15; q2 = l >> 4;
        s1 = (const u32x4*)(hbase + (size_t)(b0 + bb) * 1024 + c * 32 + q2 * 8);
        m = tid + 1024;    l = m & 63; c = m >> 6; bb = l & 15; q2 = l >> 4;
        s2 = (const u32x4*)(hbase + (size_t)(b0 + bb) * 1024 + c * 32 + q2 * 8);
        m = tid + 1536;    l = m & 63; c = m >> 6; bb = l & 15; q2 = l >> 4;
        s3 = (const u32x4*)(hbase + (size_t)(b0 + bb) * 1024 + c * 32 + q2 * 8);
      }
      v0 = *s0; v1 = *s1; v2 = *s2; v3 = *s3;   // plain first attempt (cached)
      const unsigned P = 0xAAAAAAAAu;
      int need =
          (v0[0] == P) | (v0[1] == P) | (v0[2] == P) | (v0[3] == P) |
          (v1[0] == P) | (v1[1] == P) | (v1[2] == P) | (v1[3] == P) |
          (v2[0] == P) | (v2[1] == P) | (v2[2] == P) | (v2[3] == P) |
          (v3[0] == P) | (v3[1] == P) | (v3[2] == P) | (v3[3] == P);
      int guard = 0;
      while (need) {
        // Re-load all 4 chunks uncached in parallel (idempotent: poison ->
        // final is the only transition). One vmcnt for all four.
        asm volatile(
            "global_load_dwordx4 %0, %4, off sc0 sc1\n\t"
            "global_load_dwordx4 %1, %5, off sc0 sc1\n\t"
            "global_load_dwordx4 %2, %6, off sc0 sc1\n\t"
            "global_load_dwordx4 %3, %7, off sc0 sc1\n\t"
            "s_waitcnt vmcnt(0)"
            : "=&v"(v0), "=&v"(v1), "=&v"(v2), "=&v"(v3)
            : "v"((unsigned long long)(uintptr_t)s0),
              "v"((unsigned long long)(uintptr_t)s1),
              "v"((unsigned long long)(uintptr_t)s2),
              "v"((unsigned long long)(uintptr_t)s3)
            : "memory");
        need =
            (v0[0] == P) | (v0[1] == P) | (v0[2] == P) | (v0[3] == P) |
            (v1[0] == P) | (v1[1] == P) | (v1[2] == P) | (v1[3] == P) |
            (v2[0] == P) | (v2[1] == P) | (v2[2] == P) | (v2[3] == P) |
            (v3[0] == P) | (v3[1] == P) | (v3[2] == P) | (v3[3] == P);
        if (++guard > (1 << 18)) break;  // fail-safe: proceed (fails check loudly)
      }
      *(u32x4*)&Abuf[(size_t)(tid) * 8]          = v0;
      *(u32x4*)&Abuf[(size_t)(tid + 512) * 8]    = v1;
      *(u32x4*)&Abuf[(size_t)(tid + 1024) * 8]   = v2;
      *(u32x4*)&Abuf[(size_t)(tid + 1536) * 8]   = v3;
      __syncthreads();  // B2: Abuf ready
    }

    // ---- xp for this step (issued early; consumed ~after MFMA)
    float xpv[4];
#pragma unroll
    for (int rr = 0; rr < 4; ++rr)
      xpv[rr] = bf2f(xp[((size_t)s * 128 + b0 + q * 4 + rr) * 1024 + gcol]);

    // ---- MFMA: 16x16 tile over K=1024, two independent chains
    f32x4 acc0 = (f32x4){0.f, 0.f, 0.f, 0.f};
    f32x4 acc1 = (f32x4){0.f, 0.f, 0.f, 0.f};
#pragma unroll
    for (int c = 0; c < 16; ++c) {
      short8 a0 = *(const short8*)&Abuf[(size_t)(2 * c) * 512 + lane * 8];
      short8 a1 = *(const short8*)&Abuf[(size_t)(2 * c + 1) * 512 + lane * 8];
      acc0 = __builtin_amdgcn_mfma_f32_16x16x32_bf16(a0, Bfrag[2 * c], acc0, 0, 0, 0);
      acc1 = __builtin_amdgcn_mfma_f32_16x16x32_bf16(a1, Bfrag[2 * c + 1], acc1, 0, 0, 0);
    }

    // ---- h = tanh(acc + xp); pack wave tile [batch 16][col 16] (stride 32)
    float hv4[4];
#pragma unroll
    for (int rr = 0; rr < 4; ++rr) {
      hv4[rr] = ftanh(acc0[rr] + acc1[rr] + xpv[rr]);
      ptile[w][(q * 4 + rr) * 32 + r] = f2bf(hv4[rr]);
    }
    __syncthreads();  // B3: ptile visible (cross-lane via LDS; proven form)

    // ---- publish h[s] slice: 32 lanes store 16 rows x 2 dwordx4 (sc0 sc1).
    // No ack, no tag: the data IS the readiness signal (sentinel protocol).
    if (lane < 32) {
      int row = lane & 15, half = lane >> 4;
      u32x4 v = *(const u32x4*)&ptile[w][row * 32 + half * 8];
      unsigned long long addr = (unsigned long long)(uintptr_t)(
          hs + ((size_t)s * 128 + b0 + row) * 1024 + p * 128 + w * 16 + half * 8);
      asm volatile("global_store_dwordx4 %0, %1, off sc0 sc1"
                   :: "v"(addr), "v"(v) : "memory");
    }

    // ---- fused head (off critical path)
#pragma unroll
    for (int rr = 0; rr < 4; ++rr) {
      float pp = hv4[rr] * wfcv;
      pp += __shfl_xor(pp, 1, 64);
      pp += __shfl_xor(pp, 2, 64);
      pp += __shfl_xor(pp, 4, 64);
      pp += __shfl_xor(pp, 8, 64);
      if (r == 0) {
        if (p == 0 && w == 0) pp += bfcv;
        atomicAdd(out + (size_t)s * 128 + b0 + q * 4 + rr, pp);
      }
    }
  }
}

// ---------------- launcher --------------------------------------------------
extern "C" void kernel_launch(void* const* d_in, const int* in_sizes, int n_in,
                              void* d_out, int out_size, void* d_ws, size_t ws_size,
                              hipStream_t stream) {
  (void)in_sizes; (void)n_in; (void)ws_size;
  const float* x   = (const float*)d_in[0];
  const float* Wih = (const float*)d_in[1];
  const float* Whh = (const float*)d_in[2];
  const float* bih = (const float*)d_in[3];
  const float* bhh = (const float*)d_in[4];
  const float* Wfc = (const float*)d_in[5];
  const float* bfc = (const float*)d_in[6];
  float* out = (float*)d_out;

  char* ws = (char*)d_ws;
  // Layout: xp 64 MB @0 | hs 64 MB @64MB | xb 32 MB aliases hs strips 0..127
  // (dead before scan) | wb 1 MB @96MB aliases strips 128..131. scrub_kernel
  // re-poisons strips 1..131 after gemm_xp so the sentinel protocol sees
  // 0xAA everywhere pre-publish. Strip 0 is never read (h0 is local).
  unsigned short* xp = (unsigned short*)(ws);
  unsigned short* hs = (unsigned short*)(ws + 67108864);
  unsigned short* xb = (unsigned short*)(ws + 67108864);
  unsigned short* wb = (unsigned short*)(ws + 67108864 + 33554432);

  // d_out is 0xAA-poisoned; head accumulates via atomics -> zero it.
  hipMemsetAsync(out, 0, (size_t)out_size * 4, stream);

  cvt_kernel<<<8192, 256, 0, stream>>>(x, xb, 2097152);     // x fp32 -> bf16
  cvt_kernel<<<256, 256, 0, stream>>>(Wih, wb, 65536);      // W_ih fp32 -> bf16
  gemm_xp<<<2048, 256, 0, stream>>>(xb, wb, bih, bhh, xp);  // xp = x@W_ih^T + b
  // re-poison hs strips 1..131 (bytes [256KB, 132*256KB) past hs base)
  scrub_kernel<<<8384, 256, 0, stream>>>(
      (unsigned*)(ws + 67108864 + 262144), 2146304);
  scan_kernel<<<64, 512, 0, stream>>>(Whh, xp, Wfc, bfc, hs, out);
}

// Round 4
// 1377.357 us; speedup vs baseline: 1.1497x; 1.0032x over previous
//
#include <hip/hip_runtime.h>
#include <stdint.h>

// Problem dims (fixed): T=256, B=128, I=512, H=1024, O=1
typedef __attribute__((ext_vector_type(8))) short short8;
typedef __attribute__((ext_vector_type(4))) float f32x4;
typedef __attribute__((ext_vector_type(4))) unsigned int u32x4;

__device__ __forceinline__ unsigned short f2bf(float f) {
  unsigned u = __float_as_uint(f);
  u += 0x7FFFu + ((u >> 16) & 1u);   // RNE
  return (unsigned short)(u >> 16);
}
__device__ __forceinline__ float bf2f(unsigned short s) {
  return __uint_as_float(((unsigned)s) << 16);
}
__device__ __forceinline__ float ftanh(float x) {
  float e = __expf(2.0f * x);
  return 1.0f - 2.0f / (e + 1.0f);
}

// ---------------- fp32 -> bf16 convert (vectorized, 8 elem/thread) ----------
__global__ __launch_bounds__(256) void cvt_kernel(const float* __restrict__ in,
                                                  unsigned short* __restrict__ out,
                                                  int n8) {
  int i = blockIdx.x * 256 + threadIdx.x;
  if (i >= n8) return;
  const float4* p = (const float4*)in + (size_t)i * 2;
  float4 a = p[0], b = p[1];
  uint4 o;
  o.x = (unsigned)f2bf(a.x) | ((unsigned)f2bf(a.y) << 16);
  o.y = (unsigned)f2bf(a.z) | ((unsigned)f2bf(a.w) << 16);
  o.z = (unsigned)f2bf(b.x) | ((unsigned)f2bf(b.y) << 16);
  o.w = (unsigned)f2bf(b.z) | ((unsigned)f2bf(b.w) << 16);
  ((uint4*)out)[i] = o;
}

// ---------------- re-poison hs strips 1..131 (aliased by dead xb/wb) --------
// Sentinel protocol needs every readable hs strip to be 0xAA-poison before
// the first publish. Separate dispatch => completes before any scan publish;
// dispatch-boundary L2 writeback+invalidate makes poison globally visible.
__global__ __launch_bounds__(256) void scrub_kernel(unsigned* __restrict__ dst,
                                                    int n4) {
  int i = blockIdx.x * 256 + threadIdx.x;
  if (i >= n4) return;
  ((u32x4*)dst)[i] = (u32x4){0xAAAAAAAAu, 0xAAAAAAAAu, 0xAAAAAAAAu, 0xAAAAAAAAu};
}

// ---------------- xp GEMM: xp[m][n] = sum_k x[m][k]*W_ih[n][k] + b_ih[n]+b_hh[n]
__global__ __launch_bounds__(256) void gemm_xp(const unsigned short* __restrict__ A,
                                               const unsigned short* __restrict__ Bw,
                                               const float* __restrict__ b_ih,
                                               const float* __restrict__ b_hh,
                                               unsigned short* __restrict__ xp) {
  __shared__ unsigned short Al[8192];
  __shared__ unsigned short Bl[8192];
  int tid = threadIdx.x, lane = tid & 63, w = tid >> 6;
  int wm = w & 1, wn = w >> 1;
  int bx = blockIdx.x;
  int m0 = (bx >> 3) * 128, n0 = (bx & 7) * 128;

  f32x4 acc[4][4];
#pragma unroll
  for (int i = 0; i < 4; ++i)
#pragma unroll
    for (int jq = 0; jq < 4; ++jq) acc[i][jq] = (f32x4){0.f, 0.f, 0.f, 0.f};

  for (int kb = 0; kb < 512; kb += 64) {
#pragma unroll
    for (int i = 0; i < 4; ++i) {
      int S = (w * 4 + i) * 64 + lane;
      int row = S >> 3, pg = S & 7;
      int gk = ((pg ^ (row & 7)) << 3);
      const unsigned short* ga = A + (size_t)(m0 + row) * 512 + kb + gk;
      const unsigned short* gb = Bw + (size_t)(n0 + row) * 512 + kb + gk;
      __builtin_amdgcn_global_load_lds(
          (const __attribute__((address_space(1))) unsigned int*)ga,
          (__attribute__((address_space(3))) unsigned int*)&Al[(size_t)((w * 4 + i) * 64) * 8],
          16, 0, 0);
      __builtin_amdgcn_global_load_lds(
          (const __attribute__((address_space(1))) unsigned int*)gb,
          (__attribute__((address_space(3))) unsigned int*)&Bl[(size_t)((w * 4 + i) * 64) * 8],
          16, 0, 0);
    }
    asm volatile("s_waitcnt vmcnt(0)" ::: "memory");
    __syncthreads();

#pragma unroll
    for (int c = 0; c < 2; ++c) {
      short8 av[4], bv[4];
      int gg = c * 4 + (lane >> 4);
#pragma unroll
      for (int mt = 0; mt < 4; ++mt) {
        int rowa = wm * 64 + mt * 16 + (lane & 15);
        av[mt] = *(const short8*)&Al[(rowa * 8 + (gg ^ (rowa & 7))) * 8];
        int rowb = wn * 64 + mt * 16 + (lane & 15);
        bv[mt] = *(const short8*)&Bl[(rowb * 8 + (gg ^ (rowb & 7))) * 8];
      }
#pragma unroll
      for (int mt = 0; mt < 4; ++mt)
#pragma unroll
        for (int nt = 0; nt < 4; ++nt)
          acc[mt][nt] = __builtin_amdgcn_mfma_f32_16x16x32_bf16(av[mt], bv[nt], acc[mt][nt], 0, 0, 0);
    }
    __syncthreads();
  }

  int cl = lane & 15, qd = lane >> 4;
#pragma unroll
  for (int nt = 0; nt < 4; ++nt) {
    int col = n0 + wn * 64 + nt * 16 + cl;
    float bias = b_ih[col] + b_hh[col];
#pragma unroll
    for (int mt = 0; mt < 4; ++mt) {
#pragma unroll
      for (int r = 0; r < 4; ++r) {
        int m = m0 + wm * 64 + mt * 16 + qd * 4 + r;
        xp[(size_t)m * 1024 + col] = f2bf(acc[mt][nt][r] + bias);
      }
    }
  }
}

// ---------------- the scan + fused head ------------------------------------
// 64 WGs x 512 threads (8 waves): group g = blk>>3 (16 batches), producer
// p = blk&7 owns cols [p*128, p*128+128); wave w owns the 16x16 tile at
// cols p*128+w*16. W_hh B-frags: 128 VGPRs/wave. Sentinel rendezvous
// (r2-proven): publishes at fresh per-step addresses; consumers validate
// the DATA against 0xAA workspace poison (any 16B chunk with a poison
// dword = not yet published; >=4B store atomicity makes tearing
// detectable). First attempt is a plain cached load; retries bypass down
// to the rendezvous scope, so stale lines (always poison) cannot wedge
// silently. SCOPE (r4 single change): sc1-only = DEVICE scope (sc1:sc0 =
// 0b10) on publish + retries -- rendezvous at MALL, the cross-XCD
// coherence point -- replacing r2's sc0 sc1 SYSTEM scope whose
// host-coherence semantics forced HBM-level trips (FETCH_SIZE 345 MB =
// strip pulls missing MALL). r1/r3's failures are explained by the same
// encoding: their "fast" paths used CU-scope stores + SE-scope loads,
// which are architecturally invisible cross-CU. Device scope is exactly
// what device-scope atomics use -- the proven cross-XCD meeting point.
// False-ready needs a published bf16 pair == (0xAAAA,0xAAAA): P ~ 1e-23.
// Head (O=1) fused via shfl-reduce + atomicAdd off the critical path.
__global__ __launch_bounds__(512, 1) void scan_kernel(
    const float* __restrict__ Whh, const unsigned short* __restrict__ xp,
    const float* __restrict__ Wfc, const float* __restrict__ bfc,
    unsigned short* __restrict__ hs, float* __restrict__ out) {
  __shared__ __align__(16) unsigned short Abuf[2048 * 8];     // 32 KB, piece m @ Abuf[m*8]
  __shared__ __align__(16) unsigned short ptile[8][16 * 32];  // 8 KB pack tiles
  const int tid = threadIdx.x;
  const int lane = tid & 63, w = tid >> 6;
  const int g = blockIdx.x >> 3, p = blockIdx.x & 7;
  const int r = lane & 15, q = lane >> 4;
  const int b0 = g * 16;
  const int gcol = p * 128 + w * 16 + r;   // this lane's output column
  const float bfcv = bfc[0];
  const float wfcv = Wfc[gcol];

  // ---- W_hh -> register B-frags: lane (r,q) holds W[gcol][c*32+q*8 ..+7]
  short8 Bfrag[32];
  {
    const float* wsrc = Whh + (size_t)gcol * 1024 + q * 8;
#pragma unroll
    for (int c = 0; c < 32; ++c) {
      float4 v0 = *(const float4*)(wsrc + c * 32);
      float4 v1 = *(const float4*)(wsrc + c * 32 + 4);
      short8 sv;
      sv[0] = (short)f2bf(v0.x); sv[1] = (short)f2bf(v0.y);
      sv[2] = (short)f2bf(v0.z); sv[3] = (short)f2bf(v0.w);
      sv[4] = (short)f2bf(v1.x); sv[5] = (short)f2bf(v1.y);
      sv[6] = (short)f2bf(v1.z); sv[7] = (short)f2bf(v1.w);
      Bfrag[c] = sv;
    }
  }

  // ---- step 0: full h0 = tanh(xp[0]) for this group, locally, into Abuf.
  // Piece m (c=m>>6, l=m&63): batch l&15, cols c*32 + (l>>4)*8 ..+7.
  {
#pragma unroll
    for (int i = 0; i < 4; ++i) {
      int m = tid + i * 512;
      int l = m & 63, c = m >> 6;
      int bb = l & 15, q2 = l >> 4;
      const unsigned short* src = xp + (size_t)(b0 + bb) * 1024 + c * 32 + q2 * 8;
      u32x4 xv = *(const u32x4*)src;
      const unsigned short* xs = (const unsigned short*)&xv;
      short8 sv;
      float pp = 0.f;
#pragma unroll
      for (int jj = 0; jj < 8; ++jj) {
        float h = ftanh(bf2f(xs[jj]));
        sv[jj] = (short)f2bf(h);
        pp += h * Wfc[c * 32 + q2 * 8 + jj];
      }
      *(short8*)&Abuf[(size_t)m * 8] = sv;
      if (p == 0) {               // head t=0: one WG per group contributes
        if (m < 16) pp += bfcv;   // c==0,q2==0: once per batch
        atomicAdd(out + b0 + bb, pp);
      }
    }
  }
  __syncthreads();  // Abuf(h0) ready for s=1

  for (int s = 1; s < 256; ++s) {
    if (s >= 2) {
      __syncthreads();  // B1: prev step's Abuf reads done; safe to refill

      // ---- validated strip load of h[s-1] -> Abuf. 4 chunks/thread.
      const unsigned short* hbase = hs + (size_t)(s - 1) * 131072;
      u32x4 v0, v1, v2, v3;
      const u32x4 *s0, *s1, *s2, *s3;
      {
        int m, l, c, bb, q2;
        m = tid;           l = m & 63; c = m >> 6; bb = l & 15; q2 = l >> 4;
        s0 = (const u32x4*)(hbase + (size_t)(b0 + bb) * 1024 + c * 32 + q2 * 8);
        m = tid + 512;     l = m & 63; c = m >> 6; bb = l & 15; q2 = l >> 4;
        s1 = (const u32x4*)(hbase + (size_t)(b0 + bb) * 1024 + c * 32 + q2 * 8);
        m = tid + 1024;    l = m & 63; c = m >> 6; bb = l & 15; q2 = l >> 4;
        s2 = (const u32x4*)(hbase + (size_t)(b0 + bb) * 1024 + c * 32 + q2 * 8);
        m = tid + 1536;    l = m & 63; c = m >> 6; bb = l & 15; q2 = l >> 4;
        s3 = (const u32x4*)(hbase + (size_t)(b0 + bb) * 1024 + c * 32 + q2 * 8);
      }
      v0 = *s0; v1 = *s1; v2 = *s2; v3 = *s3;   // plain first attempt (cached)
      const unsigned P = 0xAAAAAAAAu;
      int need =
          (v0[0] == P) | (v0[1] == P) | (v0[2] == P) | (v0[3] == P) |
          (v1[0] == P) | (v1[1] == P) | (v1[2] == P) | (v1[3] == P) |
          (v2[0] == P) | (v2[1] == P) | (v2[2] == P) | (v2[3] == P) |
          (v3[0] == P) | (v3[1] == P) | (v3[2] == P) | (v3[3] == P);
      int guard = 0;
      while (need) {
        // Re-load all 4 chunks at DEVICE scope (sc1 only): bypasses L1/L2
        // down to the MALL, where device-scoped publishes rendezvous.
        // Idempotent (poison -> final is the only transition); one vmcnt.
        asm volatile(
            "global_load_dwordx4 %0, %4, off sc1\n\t"
            "global_load_dwordx4 %1, %5, off sc1\n\t"
            "global_load_dwordx4 %2, %6, off sc1\n\t"
            "global_load_dwordx4 %3, %7, off sc1\n\t"
            "s_waitcnt vmcnt(0)"
            : "=&v"(v0), "=&v"(v1), "=&v"(v2), "=&v"(v3)
            : "v"((unsigned long long)(uintptr_t)s0),
              "v"((unsigned long long)(uintptr_t)s1),
              "v"((unsigned long long)(uintptr_t)s2),
              "v"((unsigned long long)(uintptr_t)s3)
            : "memory");
        need =
            (v0[0] == P) | (v0[1] == P) | (v0[2] == P) | (v0[3] == P) |
            (v1[0] == P) | (v1[1] == P) | (v1[2] == P) | (v1[3] == P) |
            (v2[0] == P) | (v2[1] == P) | (v2[2] == P) | (v2[3] == P) |
            (v3[0] == P) | (v3[1] == P) | (v3[2] == P) | (v3[3] == P);
        if (++guard > (1 << 18)) break;  // fail-safe: proceed (fails check loudly)
      }
      *(u32x4*)&Abuf[(size_t)(tid) * 8]          = v0;
      *(u32x4*)&Abuf[(size_t)(tid + 512) * 8]    = v1;
      *(u32x4*)&Abuf[(size_t)(tid + 1024) * 8]   = v2;
      *(u32x4*)&Abuf[(size_t)(tid + 1536) * 8]   = v3;
      __syncthreads();  // B2: Abuf ready
    }

    // ---- xp for this step (issued early; consumed ~after MFMA)
    float xpv[4];
#pragma unroll
    for (int rr = 0; rr < 4; ++rr)
      xpv[rr] = bf2f(xp[((size_t)s * 128 + b0 + q * 4 + rr) * 1024 + gcol]);

    // ---- MFMA: 16x16 tile over K=1024, two independent chains
    f32x4 acc0 = (f32x4){0.f, 0.f, 0.f, 0.f};
    f32x4 acc1 = (f32x4){0.f, 0.f, 0.f, 0.f};
#pragma unroll
    for (int c = 0; c < 16; ++c) {
      short8 a0 = *(const short8*)&Abuf[(size_t)(2 * c) * 512 + lane * 8];
      short8 a1 = *(const short8*)&Abuf[(size_t)(2 * c + 1) * 512 + lane * 8];
      acc0 = __builtin_amdgcn_mfma_f32_16x16x32_bf16(a0, Bfrag[2 * c], acc0, 0, 0, 0);
      acc1 = __builtin_amdgcn_mfma_f32_16x16x32_bf16(a1, Bfrag[2 * c + 1], acc1, 0, 0, 0);
    }

    // ---- h = tanh(acc + xp); pack wave tile [batch 16][col 16] (stride 32)
    float hv4[4];
#pragma unroll
    for (int rr = 0; rr < 4; ++rr) {
      hv4[rr] = ftanh(acc0[rr] + acc1[rr] + xpv[rr]);
      ptile[w][(q * 4 + rr) * 32 + r] = f2bf(hv4[rr]);
    }
    __syncthreads();  // B3: ptile visible (cross-lane via LDS; proven form)

    // ---- publish h[s] slice: 32 lanes store 16 rows x 2 dwordx4 at DEVICE
    // scope (sc1). No ack, no tag: the data IS the readiness signal.
    if (lane < 32) {
      int row = lane & 15, half = lane >> 4;
      u32x4 v = *(const u32x4*)&ptile[w][row * 32 + half * 8];
      unsigned long long addr = (unsigned long long)(uintptr_t)(
          hs + ((size_t)s * 128 + b0 + row) * 1024 + p * 128 + w * 16 + half * 8);
      asm volatile("global_store_dwordx4 %0, %1, off sc1"
                   :: "v"(addr), "v"(v) : "memory");
    }

    // ---- fused head (off critical path)
#pragma unroll
    for (int rr = 0; rr < 4; ++rr) {
      float pp = hv4[rr] * wfcv;
      pp += __shfl_xor(pp, 1, 64);
      pp += __shfl_xor(pp, 2, 64);
      pp += __shfl_xor(pp, 4, 64);
      pp += __shfl_xor(pp, 8, 64);
      if (r == 0) {
        if (p == 0 && w == 0) pp += bfcv;
        atomicAdd(out + (size_t)s * 128 + b0 + q * 4 + rr, pp);
      }
    }
  }
}

// ---------------- launcher --------------------------------------------------
extern "C" void kernel_launch(void* const* d_in, const int* in_sizes, int n_in,
                              void* d_out, int out_size, void* d_ws, size_t ws_size,
                              hipStream_t stream) {
  (void)in_sizes; (void)n_in; (void)ws_size;
  const float* x   = (const float*)d_in[0];
  const float* Wih = (const float*)d_in[1];
  const float* Whh = (const float*)d_in[2];
  const float* bih = (const float*)d_in[3];
  const float* bhh = (const float*)d_in[4];
  const float* Wfc = (const float*)d_in[5];
  const float* bfc = (const float*)d_in[6];
  float* out = (float*)d_out;

  char* ws = (char*)d_ws;
  // Layout: xp 64 MB @0 | hs 64 MB @64MB | xb 32 MB aliases hs strips 0..127
  // (dead before scan) | wb 1 MB @96MB aliases strips 128..131. scrub_kernel
  // re-poisons strips 1..131 after gemm_xp so the sentinel protocol sees
  // 0xAA everywhere pre-publish. Strip 0 is never read (h0 is local).
  unsigned short* xp = (unsigned short*)(ws);
  unsigned short* hs = (unsigned short*)(ws + 67108864);
  unsigned short* xb = (unsigned short*)(ws + 67108864);
  unsigned short* wb = (unsigned short*)(ws + 67108864 + 33554432);

  // d_out is 0xAA-poisoned; head accumulates via atomics -> zero it.
  hipMemsetAsync(out, 0, (size_t)out_size * 4, stream);

  cvt_kernel<<<8192, 256, 0, stream>>>(x, xb, 2097152);     // x fp32 -> bf16
  cvt_kernel<<<256, 256, 0, stream>>>(Wih, wb, 65536);      // W_ih fp32 -> bf16
  gemm_xp<<<2048, 256, 0, stream>>>(xb, wb, bih, bhh, xp);  // xp = x@W_ih^T + b
  // re-poison hs strips 1..131 (bytes [256KB, 132*256KB) past hs base)
  scrub_kernel<<<8384, 256, 0, stream>>>(
      (unsigned*)(ws + 67108864 + 262144), 2146304);
  scan_kernel<<<64, 512, 0, stream>>>(Whh, xp, Wfc, bfc, hs, out);
}